// Round 4
// baseline (6632.742 us; speedup 1.0000x reference)
//
#include <hip/hip_runtime.h>
#include <cstddef>

#define LOG2E 1.4426950408889634f
#define LN2   0.6931471805599453f

typedef float f32x2 __attribute__((ext_vector_type(2)));
typedef float f32x4 __attribute__((ext_vector_type(4)));

constexpr int K_    = 256;
constexpr int T_    = 2048;
constexpr int DMAX_ = 64;
constexpr int B_    = 16;

__device__ __forceinline__ float fexp2(float x) { return __builtin_amdgcn_exp2f(x); }
__device__ __forceinline__ float flog2(float x) { return __builtin_amdgcn_logf(x); }

// 1024 threads = 16 waves, 4 waves/SIMD (reg budget 128/wave).
// lane = q*16 + jl  (q = i-quarter 0..3), column j = 16*w + jl.
// All 4 q-partials of a column live in ONE wave -> cross-q reduce by shfl_xor,
// duration-age handoff by shfl_up(16). One barrier/step (p broadcast).
// Per thread: P2[32] = exp(A[i][j]) packed, i in [64q,64q+64)   (64 VGPRs)
//             pD2[8] = exp(D[j][16q+k]) packed, ages 16q+1..16q+16
//             v2[8]  = linear duration buffer (column-anchored), ages 16q+1..16q+16
__global__ __launch_bounds__(1024, 4)
void hsmm_fwd_kernel(const float* __restrict__ logB,   // [B,T,K]
                     const float* __restrict__ pi,     // [K]
                     const float* __restrict__ A,      // [K,K]
                     const float* __restrict__ D,      // [K,DMAX]
                     float* __restrict__ out)          // [16] loglik ++ [B,T,K] alphas
{
    const int b    = blockIdx.x;
    const int tid  = threadIdx.x;
    const int w    = tid >> 6;
    const int lane = tid & 63;
    const int q    = lane >> 4;        // i-quarter
    const int jl   = lane & 15;
    const int j    = (w << 4) | jl;    // state column

    alignas(16) __shared__ float lds_p[2][K_];     // ping-pong by t&1
    alignas(16) __shared__ float lds_red[2][16];   // per-wave alpha max

    // ---- init: transition probs (linear, packed) ----
    f32x2 P2[32];
    {
        const float* Abase = A + (size_t)(64 * q) * K_ + j;
        #pragma unroll
        for (int k = 0; k < 32; ++k) {
            P2[k].x = fexp2(Abase[(size_t)(2 * k + 0) * K_] * LOG2E);
            P2[k].y = fexp2(Abase[(size_t)(2 * k + 1) * K_] * LOG2E);
        }
    }
    f32x2 pD2[8];
    {
        const float* Dbase = D + (size_t)j * DMAX_ + 16 * q;
        #pragma unroll
        for (int k = 0; k < 8; ++k) {
            pD2[k].x = fexp2(Dbase[2 * k + 0] * LOG2E);
            pD2[k].y = fexp2(Dbase[2 * k + 1] * LOG2E);
        }
    }

    f32x2 v2[8];
    #pragma unroll
    for (int k = 0; k < 8; ++k) { v2[k].x = 0.0f; v2[k].y = 0.0f; }
    if (q == 0) v2[0].x = 1.0f;         // age-1 slot holds pi (anchor = pi2)
    float mcol     = pi[j] * LOG2E;     // column anchor (base-2), same across q
    float cumb     = 0.0f;
    float m_anchor = 0.0f;              // lagged global max anchor

    const float* logB_ptr   = logB + (size_t)b * T_ * K_ + j;
    float*       alphas_ptr = out + 16 + (size_t)b * T_ * K_ + j;
    float bload = *logB_ptr;            // t = 0 emission

    for (int t = 0; t < T_; ++t) {
        const int s = t & 1;
        cumb += bload * LOG2E;

        // ---- duration partial sum, cross-q reduce in-wave ----
        f32x2 s0 = {0.f, 0.f}, s1 = {0.f, 0.f};
        #pragma unroll
        for (int k = 0; k < 8; k += 2) {
            asm("v_pk_fma_f32 %0, %1, %2, %0" : "+v"(s0) : "v"(v2[k + 0]), "v"(pD2[k + 0]));
            asm("v_pk_fma_f32 %0, %1, %2, %0" : "+v"(s1) : "v"(v2[k + 1]), "v"(pD2[k + 1]));
        }
        float S = (s0.x + s0.y) + (s1.x + s1.y);
        S += __shfl_xor(S, 16, 64);
        S += __shfl_xor(S, 32, 64);     // all 4 q-lanes now hold full column sum

        // ---- alpha, p ----
        float alpha2 = cumb + mcol + flog2(S);
        float p_j    = fexp2(alpha2 - m_anchor);
        if (q == 0) {
            lds_p[s][j] = p_j;
            alphas_ptr[(size_t)t * K_] = alpha2 * LN2;
        }
        // wave max of alpha (covers this wave's 16 columns)
        float wm = alpha2;
        #pragma unroll
        for (int off = 1; off < 64; off <<= 1)
            wm = fmaxf(wm, __shfl_xor(wm, off, 64));
        if (lane == 0) lds_red[s][w] = wm;
        __syncthreads();   // the ONE barrier: lds_p / lds_red published

        // prefetch next emission (overlaps matvec)
        if (t + 1 < T_) bload = logB_ptr[(size_t)(t + 1) * K_];

        // ---- matvec partial: sum_{i in quarter} p[i] * P[i][j] ----
        const f32x4* p4 = (const f32x4*)lds_p[s] + 16 * q;
        f32x2 a0 = {0.f, 0.f}, a1 = {0.f, 0.f}, a2 = {0.f, 0.f}, a3 = {0.f, 0.f};
        #pragma unroll
        for (int g = 0; g < 16; g += 2) {
            f32x4 pv0 = p4[g];
            f32x4 pv1 = p4[g + 1];
            f32x2 pv0lo = pv0.lo, pv0hi = pv0.hi, pv1lo = pv1.lo, pv1hi = pv1.hi;
            asm("v_pk_fma_f32 %0, %1, %2, %0" : "+v"(a0) : "v"(pv0lo), "v"(P2[2 * g + 0]));
            asm("v_pk_fma_f32 %0, %1, %2, %0" : "+v"(a1) : "v"(pv0hi), "v"(P2[2 * g + 1]));
            asm("v_pk_fma_f32 %0, %1, %2, %0" : "+v"(a2) : "v"(pv1lo), "v"(P2[2 * g + 2]));
            asm("v_pk_fma_f32 %0, %1, %2, %0" : "+v"(a3) : "v"(pv1hi), "v"(P2[2 * g + 3]));
        }
        float Smv = ((a0.x + a0.y) + (a1.x + a1.y)) + ((a2.x + a2.y) + (a3.x + a3.y));
        Smv += __shfl_xor(Smv, 16, 64);
        Smv += __shfl_xor(Smv, 32, 64);

        // global alpha max (anchor for NEXT step) from per-wave maxima
        const f32x4* r4 = (const f32x4*)lds_red[s];
        f32x4 r0 = r4[0], r1 = r4[1], r2 = r4[2], r3 = r4[3];
        float m_next = fmaxf(
            fmaxf(fmaxf(fmaxf(r0.x, r0.y), fmaxf(r0.z, r0.w)),
                  fmaxf(fmaxf(r1.x, r1.y), fmaxf(r1.z, r1.w))),
            fmaxf(fmaxf(fmaxf(r2.x, r2.y), fmaxf(r2.z, r2.w)),
                  fmaxf(fmaxf(r3.x, r3.y), fmaxf(r3.z, r3.w))));

        // ---- a_in, anchor update, fused shift+rescale insert ----
        float a_in2 = m_anchor + flog2(Smv);
        float v2new = a_in2 - cumb;
        float r, newval;
        if (v2new > mcol) {
            r = fexp2(mcol - v2new); newval = 1.0f; mcol = v2new;
        } else {
            r = 1.0f; newval = fexp2(v2new - mcol);
        }
        float top = __shfl_up(v2[7].y, 16, 64);   // q-1's age 16q -> my age 16q+1
        #pragma unroll
        for (int k = 7; k >= 1; --k) {
            v2[k].y = v2[k].x * r;
            v2[k].x = v2[k - 1].y * r;
        }
        v2[0].y = v2[0].x * r;
        v2[0].x = (q == 0) ? newval : top * r;

        if (t + 1 < T_) m_anchor = m_next;  // keep last-step anchor for loglik
    }

    // ---- loglik: lds_p[1] holds exp2(alpha_{T-1} - m_anchor) ----
    if (tid < 64) {
        const float* lp = lds_p[(T_ - 1) & 1];
        float sfin = lp[tid] + lp[tid + 64] + lp[tid + 128] + lp[tid + 192];
        #pragma unroll
        for (int off = 1; off < 64; off <<= 1)
            sfin += __shfl_xor(sfin, off, 64);
        if (tid == 0) out[b] = (m_anchor + flog2(sfin)) * LN2;
    }
}

extern "C" void kernel_launch(void* const* d_in, const int* in_sizes, int n_in,
                              void* d_out, int out_size, void* d_ws, size_t ws_size,
                              hipStream_t stream) {
    const float* logB = (const float*)d_in[0];   // [16,2048,256]
    const float* pi   = (const float*)d_in[1];   // [256]
    const float* A    = (const float*)d_in[2];   // [256,256]
    const float* D    = (const float*)d_in[3];   // [256,64]
    float* out = (float*)d_out;
    (void)in_sizes; (void)n_in; (void)d_ws; (void)ws_size; (void)out_size;

    hipLaunchKernelGGL(hsmm_fwd_kernel, dim3(B_), dim3(1024), 0, stream,
                       logB, pi, A, D, out);
}

// Round 5
// 2513.831 us; speedup vs baseline: 2.6385x; 2.6385x over previous
//
#include <hip/hip_runtime.h>
#include <cstddef>

#define LOG2E 1.4426950408889634f
#define LN2   0.6931471805599453f

typedef float f32x2 __attribute__((ext_vector_type(2)));
typedef float f32x4 __attribute__((ext_vector_type(4)));

constexpr int K_    = 256;
constexpr int T_    = 2048;
constexpr int DMAX_ = 64;
constexpr int B_    = 16;
constexpr int QPAD  = 68;   // quarter stride in lds_p: 68*4B -> quarters on banks {0,4,8,12}, 16B-aligned

__device__ __forceinline__ float fexp2(float x) { return __builtin_amdgcn_exp2f(x); }
__device__ __forceinline__ float flog2(float x) { return __builtin_amdgcn_logf(x); }
__device__ __forceinline__ f32x2 pk_fma(f32x2 a, f32x2 b, f32x2 c) {
    return __builtin_elementwise_fma(a, b, c);     // -> v_pk_fma_f32 (no inline asm: keeps amdgpu-no-agpr)
}
__device__ __forceinline__ f32x2 shfl_xor2(f32x2 v, int m) {
    f32x2 r; r.x = __shfl_xor(v.x, m, 64); r.y = __shfl_xor(v.y, m, 64); return r;
}

// 512 threads = 8 waves, 2 waves/SIMD, 1 block/CU (256 unified regs/wave).
// lane = q*16 + jl (q = row-quarter 0..3); columns j0 = w*16+jl, j1 = j0+128.
// Both columns ride the two lanes of each f32x2: P_ab[64] (128 regs),
// pD_ab[16], v_ab[16] (duration buffer, ages 16q+1..16q+16, column-anchored linear).
// One __syncthreads per step; cross-q reductions via shfl_xor; age handoff via shfl_up(16).
__global__ __launch_bounds__(512, 2)
void hsmm_fwd_kernel(const float* __restrict__ logB,   // [B,T,K]
                     const float* __restrict__ pi,     // [K]
                     const float* __restrict__ A,      // [K,K]
                     const float* __restrict__ D,      // [K,DMAX]
                     float* __restrict__ out)          // [16] loglik ++ [B,T,K] alphas
{
    const int b    = blockIdx.x;
    const int tid  = threadIdx.x;
    const int w    = tid >> 6;
    const int lane = tid & 63;
    const int q    = lane >> 4;
    const int jl   = lane & 15;
    const int j0   = (w << 4) | jl;    // 0..127
    const int j1   = j0 + 128;

    alignas(16) __shared__ float lds_p[2][4 * QPAD];
    alignas(16) __shared__ float lds_red[2][8];

    // ---- init: transition probs (linear, both columns packed) ----
    f32x2 Pab[64];
    {
        const float* Arow = A + (size_t)(64 * q) * K_ + j0;
        #pragma unroll
        for (int i = 0; i < 64; ++i) {
            Pab[i].x = fexp2(Arow[(size_t)i * K_      ] * LOG2E);
            Pab[i].y = fexp2(Arow[(size_t)i * K_ + 128] * LOG2E);
        }
    }
    f32x2 pDab[16];
    {
        const float* D0 = D + (size_t)j0 * DMAX_ + 16 * q;
        const float* D1 = D + (size_t)j1 * DMAX_ + 16 * q;
        #pragma unroll
        for (int a = 0; a < 16; ++a) {
            pDab[a].x = fexp2(D0[a] * LOG2E);
            pDab[a].y = fexp2(D1[a] * LOG2E);
        }
    }

    f32x2 vab[16];
    #pragma unroll
    for (int k = 0; k < 16; ++k) vab[k] = (f32x2){0.0f, 0.0f};
    if (q == 0) vab[0] = (f32x2){1.0f, 1.0f};    // age-1 slot holds pi (anchor = pi2)
    f32x2 mcol = { pi[j0] * LOG2E, pi[j1] * LOG2E };
    f32x2 cumb = { 0.0f, 0.0f };
    float m_anchor = 0.0f;

    const int po0 = (j0 >> 6) * QPAD + (j0 & 63);   // padded p-slot for column j0
    const int po1 = po0 + 2 * QPAD;                 // column j1 (quarter +2, same within-offset)

    const float* lb = logB + (size_t)b * T_ * K_;
    float*       ao = out + 16 + (size_t)b * T_ * K_;
    f32x2 bload = { lb[j0], lb[j1] };               // t = 0 emission

    for (int t = 0; t < T_; ++t) {
        const int s = t & 1;
        cumb = pk_fma(bload, (f32x2){LOG2E, LOG2E}, cumb);

        // ---- duration partial sums (both cols packed), cross-q reduce in-wave ----
        f32x2 s0 = {0.f,0.f}, s1 = {0.f,0.f}, s2 = {0.f,0.f}, s3 = {0.f,0.f};
        #pragma unroll
        for (int a = 0; a < 16; a += 4) {
            s0 = pk_fma(vab[a + 0], pDab[a + 0], s0);
            s1 = pk_fma(vab[a + 1], pDab[a + 1], s1);
            s2 = pk_fma(vab[a + 2], pDab[a + 2], s2);
            s3 = pk_fma(vab[a + 3], pDab[a + 3], s3);
        }
        f32x2 S = (s0 + s1) + (s2 + s3);
        S = S + shfl_xor2(S, 16);
        S = S + shfl_xor2(S, 32);

        // ---- alpha, p ----
        f32x2 alpha = cumb + mcol + (f32x2){flog2(S.x), flog2(S.y)};
        f32x2 p     = { fexp2(alpha.x - m_anchor), fexp2(alpha.y - m_anchor) };
        if (q == 0) {
            lds_p[s][po0] = p.x;
            lds_p[s][po1] = p.y;
            ao[(size_t)t * K_ + j0] = alpha.x * LN2;
            ao[(size_t)t * K_ + j1] = alpha.y * LN2;
        }
        float wm = fmaxf(alpha.x, alpha.y);
        #pragma unroll
        for (int off = 1; off < 16; off <<= 1)
            wm = fmaxf(wm, __shfl_xor(wm, off, 64));
        if (lane == 0) lds_red[s][w] = wm;
        __syncthreads();   // the ONE barrier: lds_p / lds_red published

        // prefetch next emission (overlaps matvec)
        if (t + 1 < T_) {
            bload.x = lb[(size_t)(t + 1) * K_ + j0];
            bload.y = lb[(size_t)(t + 1) * K_ + j1];
        }

        // ---- matvec partial: rows 64q..64q+63, both columns packed ----
        const f32x4* p4 = (const f32x4*)(&lds_p[s][q * QPAD]);
        f32x2 a0 = {0.f,0.f}, a1 = {0.f,0.f}, a2 = {0.f,0.f}, a3 = {0.f,0.f};
        #pragma unroll
        for (int g = 0; g < 16; ++g) {
            f32x4 pv = p4[g];
            a0 = pk_fma((f32x2){pv.x, pv.x}, Pab[4 * g + 0], a0);
            a1 = pk_fma((f32x2){pv.y, pv.y}, Pab[4 * g + 1], a1);
            a2 = pk_fma((f32x2){pv.z, pv.z}, Pab[4 * g + 2], a2);
            a3 = pk_fma((f32x2){pv.w, pv.w}, Pab[4 * g + 3], a3);
        }
        f32x2 Smv = (a0 + a1) + (a2 + a3);
        Smv = Smv + shfl_xor2(Smv, 16);
        Smv = Smv + shfl_xor2(Smv, 32);

        // global alpha max (anchor for NEXT step)
        f32x4 r0 = ((const f32x4*)lds_red[s])[0];
        f32x4 r1 = ((const f32x4*)lds_red[s])[1];
        float m_next = fmaxf(fmaxf(fmaxf(r0.x, r0.y), fmaxf(r0.z, r0.w)),
                             fmaxf(fmaxf(r1.x, r1.y), fmaxf(r1.z, r1.w)));

        // ---- a_in, anchor update, fused shift+rescale insert ----
        f32x2 a_in = { m_anchor + flog2(Smv.x), m_anchor + flog2(Smv.y) };
        f32x2 vnew = a_in - cumb;
        f32x2 mnew = { fmaxf(mcol.x, vnew.x), fmaxf(mcol.y, vnew.y) };
        f32x2 rsc  = { fexp2(mcol.x - mnew.x), fexp2(mcol.y - mnew.y) };
        f32x2 nv   = { fexp2(vnew.x - mnew.x), fexp2(vnew.y - mnew.y) };
        mcol = mnew;
        f32x2 top;
        top.x = __shfl_up(vab[15].x, 16, 64);   // q-1's oldest (age 16q) -> my age 16q+1
        top.y = __shfl_up(vab[15].y, 16, 64);
        #pragma unroll
        for (int k = 15; k >= 1; --k) vab[k] = vab[k - 1] * rsc;
        vab[0] = (q == 0) ? nv : top * rsc;
        if (t + 1 < T_) m_anchor = m_next;      // keep last-step anchor for loglik
    }

    // ---- loglik: lds_p[last] holds exp2(alpha_{T-1} - m_anchor) (padded layout) ----
    if (tid < 64) {
        const float* lp = lds_p[(T_ - 1) & 1];
        float sf = lp[tid] + lp[QPAD + tid] + lp[2 * QPAD + tid] + lp[3 * QPAD + tid];
        #pragma unroll
        for (int off = 1; off < 64; off <<= 1)
            sf += __shfl_xor(sf, off, 64);
        if (tid == 0) out[b] = (m_anchor + flog2(sf)) * LN2;
    }
}

extern "C" void kernel_launch(void* const* d_in, const int* in_sizes, int n_in,
                              void* d_out, int out_size, void* d_ws, size_t ws_size,
                              hipStream_t stream) {
    const float* logB = (const float*)d_in[0];   // [16,2048,256]
    const float* pi   = (const float*)d_in[1];   // [256]
    const float* A    = (const float*)d_in[2];   // [256,256]
    const float* D    = (const float*)d_in[3];   // [256,64]
    float* out = (float*)d_out;
    (void)in_sizes; (void)n_in; (void)d_ws; (void)ws_size; (void)out_size;

    hipLaunchKernelGGL(hsmm_fwd_kernel, dim3(B_), dim3(512), 0, stream,
                       logB, pi, A, D, out);
}

// Round 6
// 2253.504 us; speedup vs baseline: 2.9433x; 1.1155x over previous
//
#include <hip/hip_runtime.h>
#include <cstddef>

#define LOG2E 1.4426950408889634f
#define LN2   0.6931471805599453f

typedef float     f32x2  __attribute__((ext_vector_type(2)));
typedef float     f32x4  __attribute__((ext_vector_type(4)));
typedef _Float16  half2_t __attribute__((ext_vector_type(2)));

constexpr int K_    = 256;
constexpr int T_    = 2048;
constexpr int DMAX_ = 64;
constexpr int B_    = 16;
constexpr int QH    = 72;   // quarter stride in halves (144 B): banks {0,4,8,12}, 16B-aligned

__device__ __forceinline__ float fexp2(float x) { return __builtin_amdgcn_exp2f(x); }
__device__ __forceinline__ float flog2(float x) { return __builtin_amdgcn_logf(x); }
__device__ __forceinline__ float fdot2(half2_t a, half2_t b, float c) {
    return __builtin_amdgcn_fdot2(a, b, c, false);   // v_dot2_f32_f16
}
__device__ __forceinline__ half2_t bch2(unsigned int u) {
    return __builtin_bit_cast(half2_t, u);
}

// 512 threads = 8 waves, 2 waves/SIMD, 1 block/CU.
// lane = q*16 + jl (q = row-quarter 0..3); columns j0 = w*16+jl, j1 = j0+128.
// Persistent regs/thread: Pa/Pb[32] half2 (64 regs) = exp(A[i][j]) f16,
//   pDh[16] half2 (16 regs, col0 lo / col1 hi), vab[16] f32x2 (32 regs).
// One __syncthreads per step; cross-q reduce via shfl_xor; age handoff via shfl_up(16).
__global__ __launch_bounds__(512, 2)
void hsmm_fwd_kernel(const float* __restrict__ logB,   // [B,T,K]
                     const float* __restrict__ pi,     // [K]
                     const float* __restrict__ A,      // [K,K]
                     const float* __restrict__ D,      // [K,DMAX]
                     float* __restrict__ out)          // [16] loglik ++ [B,T,K] alphas
{
    const int b    = blockIdx.x;
    const int tid  = threadIdx.x;
    const int w    = tid >> 6;
    const int lane = tid & 63;
    const int q    = lane >> 4;
    const int jl   = lane & 15;
    const int j0   = (w << 4) | jl;    // 0..127
    const int j1   = j0 + 128;

    alignas(16) __shared__ _Float16 lds_ph[2][4][QH];   // p as f16, padded quarters
    alignas(16) __shared__ float    lds_red[2][8];

    // ---- init: transition probs f16 (linear), duration probs f16 ----
    half2_t Pa[32], Pb[32];
    {
        const float* Arow = A + (size_t)(64 * q) * K_ + j0;
        #pragma unroll
        for (int i = 0; i < 32; ++i) {
            Pa[i] = half2_t{(_Float16)fexp2(Arow[(size_t)(2 * i)     * K_] * LOG2E),
                            (_Float16)fexp2(Arow[(size_t)(2 * i + 1) * K_] * LOG2E)};
            Pb[i] = half2_t{(_Float16)fexp2(Arow[(size_t)(2 * i)     * K_ + 128] * LOG2E),
                            (_Float16)fexp2(Arow[(size_t)(2 * i + 1) * K_ + 128] * LOG2E)};
        }
    }
    half2_t pDh[16];   // age 16q+k+1: .x = col j0, .y = col j1
    {
        const float* D0 = D + (size_t)j0 * DMAX_ + 16 * q;
        const float* D1 = D + (size_t)j1 * DMAX_ + 16 * q;
        #pragma unroll
        for (int k = 0; k < 16; ++k)
            pDh[k] = half2_t{(_Float16)fexp2(D0[k] * LOG2E),
                             (_Float16)fexp2(D1[k] * LOG2E)};
    }

    f32x2 vab[16];
    #pragma unroll
    for (int k = 0; k < 16; ++k) vab[k] = (f32x2){0.0f, 0.0f};
    if (q == 0) vab[0] = (f32x2){1.0f, 1.0f};    // age-1 slot holds pi (anchor = pi2)
    f32x2 mcol = { pi[j0] * LOG2E, pi[j1] * LOG2E };
    f32x2 cumb = { 0.0f, 0.0f };
    float m_anchor = 0.0f;

    const int qq = j0 >> 6;        // quarter of j0 (0/1); j1 is quarter qq+2
    const int ii = j0 & 63;

    const float* lb = logB + (size_t)b * T_ * K_;
    float*       ao = out + 16 + (size_t)b * T_ * K_;
    f32x2 bload = { lb[j0], lb[j1] };               // t = 0 emission

    for (int t = 0; t < T_; ++t) {
        const int s = t & 1;
        cumb.x = fmaf(bload.x, LOG2E, cumb.x);
        cumb.y = fmaf(bload.y, LOG2E, cumb.y);

        // ---- duration partial sums (v f32 × pD f16 via fma_mix), reduce in-wave ----
        float d0 = 0.f, d1 = 0.f, d2 = 0.f, d3 = 0.f;
        #pragma unroll
        for (int k = 0; k < 16; k += 2) {
            d0 = fmaf(vab[k].x,     (float)pDh[k].x,     d0);
            d1 = fmaf(vab[k].y,     (float)pDh[k].y,     d1);
            d2 = fmaf(vab[k + 1].x, (float)pDh[k + 1].x, d2);
            d3 = fmaf(vab[k + 1].y, (float)pDh[k + 1].y, d3);
        }
        float Sx = d0 + d2, Sy = d1 + d3;
        Sx += __shfl_xor(Sx, 16, 64);  Sy += __shfl_xor(Sy, 16, 64);
        Sx += __shfl_xor(Sx, 32, 64);  Sy += __shfl_xor(Sy, 32, 64);

        // ---- alpha, p ----
        float ax = cumb.x + mcol.x + flog2(Sx);
        float ay = cumb.y + mcol.y + flog2(Sy);
        float px = fexp2(ax - m_anchor);
        float py = fexp2(ay - m_anchor);
        if (q == 0) {
            lds_ph[s][qq    ][ii] = (_Float16)px;
            lds_ph[s][qq + 2][ii] = (_Float16)py;
            ao[(size_t)t * K_ + j0] = ax * LN2;
            ao[(size_t)t * K_ + j1] = ay * LN2;
        }
        float wm = fmaxf(ax, ay);
        #pragma unroll
        for (int off = 1; off < 16; off <<= 1)
            wm = fmaxf(wm, __shfl_xor(wm, off, 64));
        if (lane == 0) lds_red[s][w] = wm;
        __syncthreads();   // the ONE barrier: lds_ph / lds_red published

        // prefetch next emission (overlaps matvec)
        if (t + 1 < T_) {
            bload.x = lb[(size_t)(t + 1) * K_ + j0];
            bload.y = lb[(size_t)(t + 1) * K_ + j1];
        }

        // ---- matvec partial: rows 64q..64q+63 (32 half2), both columns ----
        const uint4* pld = (const uint4*)(&lds_ph[s][q][0]);
        float m0 = 0.f, m1 = 0.f, m2 = 0.f, m3 = 0.f;
        #pragma unroll
        for (int g = 0; g < 8; ++g) {
            uint4 u = pld[g];
            half2_t h0 = bch2(u.x), h1 = bch2(u.y), h2 = bch2(u.z), h3 = bch2(u.w);
            m0 = fdot2(h0, Pa[4 * g + 0], m0);
            m1 = fdot2(h1, Pa[4 * g + 1], m1);
            m0 = fdot2(h2, Pa[4 * g + 2], m0);
            m1 = fdot2(h3, Pa[4 * g + 3], m1);
            m2 = fdot2(h0, Pb[4 * g + 0], m2);
            m3 = fdot2(h1, Pb[4 * g + 1], m3);
            m2 = fdot2(h2, Pb[4 * g + 2], m2);
            m3 = fdot2(h3, Pb[4 * g + 3], m3);
        }
        float Smvx = m0 + m1, Smvy = m2 + m3;
        Smvx += __shfl_xor(Smvx, 16, 64);  Smvy += __shfl_xor(Smvy, 16, 64);
        Smvx += __shfl_xor(Smvx, 32, 64);  Smvy += __shfl_xor(Smvy, 32, 64);

        // global alpha max (anchor for NEXT step)
        f32x4 r0 = ((const f32x4*)lds_red[s])[0];
        f32x4 r1 = ((const f32x4*)lds_red[s])[1];
        float m_next = fmaxf(fmaxf(fmaxf(r0.x, r0.y), fmaxf(r0.z, r0.w)),
                             fmaxf(fmaxf(r1.x, r1.y), fmaxf(r1.z, r1.w)));

        // ---- a_in, anchor update, fused shift+rescale insert ----
        float ainx = m_anchor + flog2(Smvx);
        float ainy = m_anchor + flog2(Smvy);
        float vnx = ainx - cumb.x,       vny = ainy - cumb.y;
        float mnx = fmaxf(mcol.x, vnx),  mny = fmaxf(mcol.y, vny);
        f32x2 rsc = { fexp2(mcol.x - mnx), fexp2(mcol.y - mny) };
        f32x2 nv  = { fexp2(vnx - mnx),    fexp2(vny - mny) };
        mcol.x = mnx;  mcol.y = mny;
        f32x2 top;
        top.x = __shfl_up(vab[15].x, 16, 64);   // q-1's oldest (age 16q) -> my age 16q+1
        top.y = __shfl_up(vab[15].y, 16, 64);
        #pragma unroll
        for (int k = 15; k >= 1; --k) vab[k] = vab[k - 1] * rsc;
        vab[0] = (q == 0) ? nv : top * rsc;
        if (t + 1 < T_) m_anchor = m_next;      // keep last-step anchor for loglik
    }

    // ---- loglik: lds_ph[last] holds f16 exp2(alpha_{T-1} - m_anchor) ----
    if (tid < 64) {
        const _Float16* lp = &lds_ph[(T_ - 1) & 1][0][0];
        float sf = (float)lp[tid] + (float)lp[QH + tid]
                 + (float)lp[2 * QH + tid] + (float)lp[3 * QH + tid];
        #pragma unroll
        for (int off = 1; off < 64; off <<= 1)
            sf += __shfl_xor(sf, off, 64);
        if (tid == 0) out[b] = (m_anchor + flog2(sf)) * LN2;
    }
}

extern "C" void kernel_launch(void* const* d_in, const int* in_sizes, int n_in,
                              void* d_out, int out_size, void* d_ws, size_t ws_size,
                              hipStream_t stream) {
    const float* logB = (const float*)d_in[0];   // [16,2048,256]
    const float* pi   = (const float*)d_in[1];   // [256]
    const float* A    = (const float*)d_in[2];   // [256,256]
    const float* D    = (const float*)d_in[3];   // [256,64]
    float* out = (float*)d_out;
    (void)in_sizes; (void)n_in; (void)d_ws; (void)ws_size; (void)out_size;

    hipLaunchKernelGGL(hsmm_fwd_kernel, dim3(B_), dim3(512), 0, stream,
                       logB, pi, A, D, out);
}

// Round 7
// 2217.889 us; speedup vs baseline: 2.9906x; 1.0161x over previous
//
#include <hip/hip_runtime.h>
#include <cstddef>

#define LOG2E 1.4426950408889634f
#define LN2   0.6931471805599453f

typedef float     f32x2   __attribute__((ext_vector_type(2)));
typedef float     f32x4   __attribute__((ext_vector_type(4)));
typedef _Float16  half2_t __attribute__((ext_vector_type(2)));

constexpr int K_    = 256;
constexpr int T_    = 2048;
constexpr int DMAX_ = 64;
constexpr int B_    = 16;
constexpr int QH    = 72;   // quarter stride in halves (144 B): banks {0,4,8,12}, 16B-aligned

__device__ __forceinline__ float fexp2(float x) { return __builtin_amdgcn_exp2f(x); }
__device__ __forceinline__ float flog2(float x) { return __builtin_amdgcn_logf(x); }
__device__ __forceinline__ float fdot2(half2_t a, half2_t b, float c) {
    return __builtin_amdgcn_fdot2(a, b, c, false);   // v_dot2_f32_f16
}
__device__ __forceinline__ half2_t bch2(unsigned int u) {
    return __builtin_bit_cast(half2_t, u);
}

// 512 threads = 8 waves, PINNED 2 waves/SIMD (amdgpu_waves_per_eu(2,2) -> 256-reg budget,
// so the allocator has no reason to push persistent arrays into AGPRs).
// lane = q*16 + jl (q = row-quarter 0..3); cw = w*16+jl in [0,128); columns j0 = 2cw, j1 = 2cw+1.
// Persistent regs/thread: Pa/Pb[32] half2 (64) = exp(A[i][j]) f16, pDf[16] f32x2 (32),
//   vab[16] f32x2 (32, duration buffer ages 16q+1..16q+16, column-anchored linear).
// One __syncthreads per step; cross-q reduce via shfl_xor; age handoff via shfl_up(16).
__global__ __launch_bounds__(512)
__attribute__((amdgpu_waves_per_eu(2, 2)))
void hsmm_fwd_kernel(const float* __restrict__ logB,   // [B,T,K]
                     const float* __restrict__ pi,     // [K]
                     const float* __restrict__ A,      // [K,K]
                     const float* __restrict__ D,      // [K,DMAX]
                     float* __restrict__ out)          // [16] loglik ++ [B,T,K] alphas
{
    const int b    = blockIdx.x;
    const int tid  = threadIdx.x;
    const int w    = tid >> 6;
    const int lane = tid & 63;
    const int q    = lane >> 4;
    const int jl   = lane & 15;
    const int cw   = (w << 4) | jl;    // 0..127
    const int j0   = cw << 1;          // even column
    const int j1   = j0 + 1;           // odd column

    alignas(16) __shared__ _Float16 lds_ph[2][4][QH];   // p as f16, padded quarters
    alignas(16) __shared__ float    lds_red[2][8];

    // ---- init: transition probs f16 (linear), duration probs f32 (linear) ----
    half2_t Pa[32], Pb[32];
    {
        const float* Arow = A + (size_t)(64 * q) * K_ + j0;
        #pragma unroll
        for (int i = 0; i < 32; ++i) {
            Pa[i] = half2_t{(_Float16)fexp2(Arow[(size_t)(2 * i)     * K_] * LOG2E),
                            (_Float16)fexp2(Arow[(size_t)(2 * i + 1) * K_] * LOG2E)};
            Pb[i] = half2_t{(_Float16)fexp2(Arow[(size_t)(2 * i)     * K_ + 1] * LOG2E),
                            (_Float16)fexp2(Arow[(size_t)(2 * i + 1) * K_ + 1] * LOG2E)};
        }
    }
    f32x2 pDf[16];   // age 16q+k+1: .x = col j0, .y = col j1
    {
        const float* D0 = D + (size_t)j0 * DMAX_ + 16 * q;
        #pragma unroll
        for (int k = 0; k < 16; ++k)
            pDf[k] = (f32x2){ fexp2(D0[k] * LOG2E), fexp2(D0[DMAX_ + k] * LOG2E) };
    }

    f32x2 vab[16];
    #pragma unroll
    for (int k = 0; k < 16; ++k) vab[k] = (f32x2){0.0f, 0.0f};
    if (q == 0) vab[0] = (f32x2){1.0f, 1.0f};    // age-1 slot holds pi (anchor = pi2)
    f32x2 mcol = { pi[j0] * LOG2E, pi[j1] * LOG2E };
    f32x2 cumb = { 0.0f, 0.0f };
    float m_anchor = 0.0f;

    const int qq = j0 >> 6;        // LDS quarter of both columns
    const int ii = j0 & 63;        // even offset within quarter

    const float* lb = logB + (size_t)b * T_ * K_ + j0;
    float*       ao = out + 16 + (size_t)b * T_ * K_ + j0;
    f32x2 bload = *(const f32x2*)lb;                // t = 0 emission (dwordx2)

    for (int t = 0; t < T_; ++t) {
        const int s = t & 1;
        cumb = __builtin_elementwise_fma(bload, (f32x2){LOG2E, LOG2E}, cumb);

        // ---- duration partial sums (16 pk_fma), cross-q reduce in-wave ----
        f32x2 s0 = {0.f,0.f}, s1 = {0.f,0.f}, s2 = {0.f,0.f}, s3 = {0.f,0.f};
        #pragma unroll
        for (int k = 0; k < 16; k += 4) {
            s0 = __builtin_elementwise_fma(vab[k + 0], pDf[k + 0], s0);
            s1 = __builtin_elementwise_fma(vab[k + 1], pDf[k + 1], s1);
            s2 = __builtin_elementwise_fma(vab[k + 2], pDf[k + 2], s2);
            s3 = __builtin_elementwise_fma(vab[k + 3], pDf[k + 3], s3);
        }
        f32x2 S = (s0 + s1) + (s2 + s3);
        S.x += __shfl_xor(S.x, 16, 64);  S.y += __shfl_xor(S.y, 16, 64);
        S.x += __shfl_xor(S.x, 32, 64);  S.y += __shfl_xor(S.y, 32, 64);

        // ---- alpha, p ----
        float ax = cumb.x + mcol.x + flog2(S.x);
        float ay = cumb.y + mcol.y + flog2(S.y);
        float px = fexp2(ax - m_anchor);
        float py = fexp2(ay - m_anchor);
        if (q == 0) {
            *(half2_t*)&lds_ph[s][qq][ii] = half2_t{(_Float16)px, (_Float16)py};
            *(f32x2*)&ao[(size_t)t * K_] = (f32x2){ ax * LN2, ay * LN2 };
        }
        float wm = fmaxf(ax, ay);
        #pragma unroll
        for (int off = 1; off < 16; off <<= 1)
            wm = fmaxf(wm, __shfl_xor(wm, off, 64));
        if (lane == 0) lds_red[s][w] = wm;
        __syncthreads();   // the ONE barrier: lds_ph / lds_red published

        // prefetch next emission (overlaps matvec)
        if (t + 1 < T_) bload = *(const f32x2*)&lb[(size_t)(t + 1) * K_];

        // ---- matvec partial: rows 64q..64q+63 (32 half2), both columns ----
        const uint4* pld = (const uint4*)(&lds_ph[s][q][0]);
        float m0 = 0.f, m1 = 0.f, m2 = 0.f, m3 = 0.f;
        #pragma unroll
        for (int g = 0; g < 8; ++g) {
            uint4 u = pld[g];
            half2_t h0 = bch2(u.x), h1 = bch2(u.y), h2 = bch2(u.z), h3 = bch2(u.w);
            m0 = fdot2(h0, Pa[4 * g + 0], m0);
            m1 = fdot2(h1, Pa[4 * g + 1], m1);
            m0 = fdot2(h2, Pa[4 * g + 2], m0);
            m1 = fdot2(h3, Pa[4 * g + 3], m1);
            m2 = fdot2(h0, Pb[4 * g + 0], m2);
            m3 = fdot2(h1, Pb[4 * g + 1], m3);
            m2 = fdot2(h2, Pb[4 * g + 2], m2);
            m3 = fdot2(h3, Pb[4 * g + 3], m3);
        }
        float Smvx = m0 + m1, Smvy = m2 + m3;
        Smvx += __shfl_xor(Smvx, 16, 64);  Smvy += __shfl_xor(Smvy, 16, 64);
        Smvx += __shfl_xor(Smvx, 32, 64);  Smvy += __shfl_xor(Smvy, 32, 64);

        // global alpha max (anchor for NEXT step)
        f32x4 r0 = ((const f32x4*)lds_red[s])[0];
        f32x4 r1 = ((const f32x4*)lds_red[s])[1];
        float m_next = fmaxf(fmaxf(fmaxf(r0.x, r0.y), fmaxf(r0.z, r0.w)),
                             fmaxf(fmaxf(r1.x, r1.y), fmaxf(r1.z, r1.w)));

        // ---- a_in, anchor update, fused shift+rescale insert ----
        float ainx = m_anchor + flog2(Smvx);
        float ainy = m_anchor + flog2(Smvy);
        float vnx = ainx - cumb.x,       vny = ainy - cumb.y;
        float mnx = fmaxf(mcol.x, vnx),  mny = fmaxf(mcol.y, vny);
        f32x2 rsc = { fexp2(mcol.x - mnx), fexp2(mcol.y - mny) };
        f32x2 nv  = { fexp2(vnx - mnx),    fexp2(vny - mny) };
        mcol.x = mnx;  mcol.y = mny;
        f32x2 top;
        top.x = __shfl_up(vab[15].x, 16, 64);   // q-1's oldest (age 16q) -> my age 16q+1
        top.y = __shfl_up(vab[15].y, 16, 64);
        #pragma unroll
        for (int k = 15; k >= 1; --k) vab[k] = vab[k - 1] * rsc;
        vab[0] = (q == 0) ? nv : top * rsc;
        if (t + 1 < T_) m_anchor = m_next;      // keep last-step anchor for loglik
    }

    // ---- loglik: lds_ph[last] holds f16 exp2(alpha_{T-1} - m_anchor) ----
    if (tid < 64) {
        const _Float16* lp = &lds_ph[(T_ - 1) & 1][0][0];
        float sf = (float)lp[tid] + (float)lp[QH + tid]
                 + (float)lp[2 * QH + tid] + (float)lp[3 * QH + tid];
        #pragma unroll
        for (int off = 1; off < 64; off <<= 1)
            sf += __shfl_xor(sf, off, 64);
        if (tid == 0) out[b] = (m_anchor + flog2(sf)) * LN2;
    }
}

extern "C" void kernel_launch(void* const* d_in, const int* in_sizes, int n_in,
                              void* d_out, int out_size, void* d_ws, size_t ws_size,
                              hipStream_t stream) {
    const float* logB = (const float*)d_in[0];   // [16,2048,256]
    const float* pi   = (const float*)d_in[1];   // [256]
    const float* A    = (const float*)d_in[2];   // [256,256]
    const float* D    = (const float*)d_in[3];   // [256,64]
    float* out = (float*)d_out;
    (void)in_sizes; (void)n_in; (void)d_ws; (void)ws_size; (void)out_size;

    hipLaunchKernelGGL(hsmm_fwd_kernel, dim3(B_), dim3(512), 0, stream,
                       logB, pi, A, D, out);
}

// Round 8
// 1886.755 us; speedup vs baseline: 3.5154x; 1.1755x over previous
//
#include <hip/hip_runtime.h>
#include <cstddef>

#define LOG2E 1.4426950408889634f
#define LN2   0.6931471805599453f

typedef float    f32x2 __attribute__((ext_vector_type(2)));
typedef float    f32x4 __attribute__((ext_vector_type(4)));
typedef _Float16 half8 __attribute__((ext_vector_type(8)));

constexpr int K_    = 256;
constexpr int T_    = 2048;
constexpr int DMAX_ = 64;
constexpr int B_    = 16;

__device__ __forceinline__ float fexp2(float x) { return __builtin_amdgcn_exp2f(x); }
__device__ __forceinline__ float flog2(float x) { return __builtin_amdgcn_logf(x); }
template<int IMM>
__device__ __forceinline__ float swzf(float v) {   // compile-time ds_swizzle, no addr VALU
    return __builtin_bit_cast(float,
        __builtin_amdgcn_ds_swizzle(__builtin_bit_cast(int, v), IMM));
}
__device__ __forceinline__ float bpermf(int addr, float v) {
    return __builtin_bit_cast(float,
        __builtin_amdgcn_ds_bpermute(addr, __builtin_bit_cast(int, v)));
}

// 512 threads = 8 waves, pinned 2 waves/SIMD. Wave w owns columns 32w..32w+31.
// Thread role: j = 32w + (lane>>1); q = lane&1 owns duration ages 32q+1..32q+32
//   (v[16] f32x2 column-anchored linear buffer, pDf[16] f32x2).
// Matvec a_in = p·P done by MFMA 16x16x32 f16: A-rows all replicated with p
//   (every D row equals p·B), B-fragments = exp(A_logits) f16 held in 64 regs
//   (AGPR-legal as MFMA operands). No cross-lane reduce needed for the matvec.
// Anchor: lag-2 block max of a_in via lds_red ping-pong (write post-barrier t,
//   read post-barrier t+1, used in phase A of t+2). One __syncthreads per step.
__global__ __launch_bounds__(512)
__attribute__((amdgpu_waves_per_eu(2, 2)))
void hsmm_fwd_kernel(const float* __restrict__ logB,   // [B,T,K]
                     const float* __restrict__ pi,     // [K]
                     const float* __restrict__ A,      // [K,K]
                     const float* __restrict__ D,      // [K,DMAX]
                     float* __restrict__ out)          // [16] loglik ++ [B,T,K] alphas
{
    const int b    = blockIdx.x;
    const int tid  = threadIdx.x;
    const int w    = tid >> 6;
    const int lane = tid & 63;
    const int j    = (w << 5) | (lane >> 1);   // column 0..255
    const int q    = lane & 1;                 // age half

    alignas(16) __shared__ _Float16 lds_ph[2][K_];    // p f16, ping-pong by t&1
    alignas(16) __shared__ float    lds_red[2][8];    // per-wave max a_in, ping-pong

    // ---- init: B-fragments (P = exp(A_logits), f16, MFMA B-layout) ----
    // B[k][n]: lane holds k = kc*32 + (lane>>4)*8 + jj, n = 32w + 16*tile + (lane&15)
    half8 Bf0[8], Bf1[8];
    {
        const int krow = (lane >> 4) * 8;
        const int n0   = (w << 5) + (lane & 15);
        #pragma unroll
        for (int kc = 0; kc < 8; ++kc) {
            #pragma unroll
            for (int jj = 0; jj < 8; ++jj) {
                const int k = kc * 32 + krow + jj;
                Bf0[kc][jj] = (_Float16)fexp2(A[(size_t)k * K_ + n0     ] * LOG2E);
                Bf1[kc][jj] = (_Float16)fexp2(A[(size_t)k * K_ + n0 + 16] * LOG2E);
            }
        }
    }
    f32x2 pDf[16];   // ages 32q+2k+1 (.x), 32q+2k+2 (.y)
    {
        const float* Dj = D + (size_t)j * DMAX_ + 32 * q;
        #pragma unroll
        for (int k = 0; k < 16; ++k)
            pDf[k] = (f32x2){ fexp2(Dj[2 * k] * LOG2E), fexp2(Dj[2 * k + 1] * LOG2E) };
    }

    f32x2 v[16];
    #pragma unroll
    for (int k = 0; k < 16; ++k) v[k] = (f32x2){0.0f, 0.0f};
    if (q == 0) v[0].x = 1.0f;          // age-1 holds pi (anchor = pi2)
    float mcol     = pi[j] * LOG2E;     // column anchor (base-2)
    float cumb     = 0.0f;
    float m_anchor = 0.0f;              // lag-2 block anchor

    const int bp_smv = ((lane >> 1) & 15) << 2;   // bpermute addr for Smv pickup

    if (tid < 8) { lds_red[0][tid] = 0.0f; lds_red[1][tid] = 0.0f; }
    __syncthreads();

    const float* lb = logB + (size_t)b * T_ * K_ + j;
    float*       ao = out + 16 + (size_t)b * T_ * K_ + j;
    float bload = *lb;                  // t = 0 emission

    for (int t = 0; t < T_; ++t) {
        const int s = t & 1;
        cumb = fmaf(bload, LOG2E, cumb);

        // ---- phase A: duration sum (16 pk_fma) + 1 swizzle cross-half ----
        f32x2 s0 = {0.f,0.f}, s1 = {0.f,0.f}, s2 = {0.f,0.f}, s3 = {0.f,0.f};
        #pragma unroll
        for (int k = 0; k < 16; k += 4) {
            s0 = __builtin_elementwise_fma(v[k + 0], pDf[k + 0], s0);
            s1 = __builtin_elementwise_fma(v[k + 1], pDf[k + 1], s1);
            s2 = __builtin_elementwise_fma(v[k + 2], pDf[k + 2], s2);
            s3 = __builtin_elementwise_fma(v[k + 3], pDf[k + 3], s3);
        }
        f32x2 sp = (s0 + s1) + (s2 + s3);
        float S = sp.x + sp.y;
        S += swzf<0x041F>(S);            // xor 1: other age-half, same column

        float alpha = cumb + mcol + flog2(S);
        float p     = fminf(fexp2(alpha - m_anchor), 60000.0f);  // f16-overflow clamp
        if (q == 0) {
            lds_ph[s][j] = (_Float16)p;
            ao[(size_t)t * K_] = alpha * LN2;
        }
        __syncthreads();   // the ONE barrier: lds_ph published

        if (t + 1 < T_) bload = lb[(size_t)(t + 1) * K_];   // prefetch

        // ---- phase B: MFMA matvec, all K=256 summed in-instruction ----
        const _Float16* pb = lds_ph[s];
        f32x4 d0 = {0.f,0.f,0.f,0.f}, d1 = {0.f,0.f,0.f,0.f};
        #pragma unroll
        for (int kc = 0; kc < 8; ++kc) {
            half8 af = *(const half8*)(pb + kc * 32 + ((lane >> 4) * 8));  // A-frag: p replicated in all rows
            d0 = __builtin_amdgcn_mfma_f32_16x16x32_f16(af, Bf0[kc], d0, 0, 0, 0);
            d1 = __builtin_amdgcn_mfma_f32_16x16x32_f16(af, Bf1[kc], d1, 0, 0, 0);
        }
        // every lane holds Smv[32w+(lane&15)] in d0.x and Smv[32w+16+(lane&15)] in d1.x
        float sv0 = bpermf(bp_smv, d0.x);
        float sv1 = bpermf(bp_smv, d1.x);
        float mySmv = (lane & 32) ? sv1 : sv0;

        // wave max of Smv -> max a_in of this wave's 32 columns (anchor feed)
        float mx = fmaxf(d0.x, d1.x);
        mx = fmaxf(mx, swzf<0x041F>(mx));
        mx = fmaxf(mx, swzf<0x081F>(mx));
        mx = fmaxf(mx, swzf<0x101F>(mx));
        mx = fmaxf(mx, swzf<0x201F>(mx));
        if (lane == 0) lds_red[s][w] = m_anchor + flog2(fmaxf(mx, 1e-30f));

        // anchor for t+2: block max of a_in written at t-1 (safe: barrier(t) between)
        f32x4 r0 = ((const f32x4*)lds_red[s ^ 1])[0];
        f32x4 r1 = ((const f32x4*)lds_red[s ^ 1])[1];
        float m_next = fmaxf(fmaxf(fmaxf(r0.x, r0.y), fmaxf(r0.z, r0.w)),
                             fmaxf(fmaxf(r1.x, r1.y), fmaxf(r1.z, r1.w)));

        // ---- a_in, fused shift+rescale insert ----
        float a_in = m_anchor + flog2(mySmv);
        float vnew = a_in - cumb;
        float mnew = fmaxf(mcol, vnew);
        float rsc  = fexp2(mcol - mnew);
        float nv   = fexp2(vnew - mnew);
        mcol = mnew;
        float hand = swzf<0x041F>(v[15].y) * rsc;   // q0's age-32 -> q1's age-33
        f32x2 rp = { rsc, rsc };
        #pragma unroll
        for (int k = 15; k >= 1; --k) {
            v[k].y = v[k].x * rsc;
            v[k].x = v[k - 1].y * rsc;
        }
        v[0].y = v[0].x * rsc;
        v[0].x = (q == 0) ? nv : hand;
        (void)rp;
        if (t + 1 < T_) m_anchor = m_next;   // keep last-step anchor for loglik
    }

    // ---- loglik: lds_ph[last] holds f16 exp2(alpha_{T-1} - m_anchor) ----
    if (tid < 64) {
        const _Float16* lp = lds_ph[(T_ - 1) & 1];
        float sf = (float)lp[tid] + (float)lp[tid + 64]
                 + (float)lp[tid + 128] + (float)lp[tid + 192];
        #pragma unroll
        for (int off = 1; off < 64; off <<= 1)
            sf += __shfl_xor(sf, off, 64);
        if (tid == 0) out[b] = (m_anchor + flog2(sf)) * LN2;
    }
}

extern "C" void kernel_launch(void* const* d_in, const int* in_sizes, int n_in,
                              void* d_out, int out_size, void* d_ws, size_t ws_size,
                              hipStream_t stream) {
    const float* logB = (const float*)d_in[0];   // [16,2048,256]
    const float* pi   = (const float*)d_in[1];   // [256]
    const float* A    = (const float*)d_in[2];   // [256,256]
    const float* D    = (const float*)d_in[3];   // [256,64]
    float* out = (float*)d_out;
    (void)in_sizes; (void)n_in; (void)d_ws; (void)ws_size; (void)out_size;

    hipLaunchKernelGGL(hsmm_fwd_kernel, dim3(B_), dim3(512), 0, stream,
                       logB, pi, A, D, out);
}